// Round 1
// baseline (63.513 us; speedup 1.0000x reference)
//
#include <hip/hip_runtime.h>

// Fused two-stage grouped conv, (1,512,14,14) fp32.
// Stage 1: t4[k,o,m,n] = sum_{i<64,j<3} x[(i*8+o), (m+j-2) mod 14, n] * w1[k,i,j]
//          (term valid only when 0 <= m+j-1 < 14; the mod-14 comes from roll(+1,H))
// Stage 2: out[i2*16+o2, m, n] = sum_{j<8,k<3} t4[o2,j,m,n+k-1] * w2[i2,j,k]  (zero-pad W)
//
// Latency-bound (14.5 MFLOP, ~0.8 MB I/O; the harness's 268 MB poison fill
// flushes L2+L3 every iteration, so all loads are cold HBM ~900cy).
// Design: ONE memory-latency round, ONE barrier.
//  - All global loads issue at t=0, no barrier in front of them:
//      waves 0-3 (t<224): 48x float2 x-loads + 12x float4 w1-loads -> REGISTERS
//      waves 5-7 (t>=320): w2 -> LDS via float4
//  - 4-way depth split combined with intra-quad shfl_xor (quarter = t&3),
//    no LDS round-trip, no extra barrier.
//  - Single __syncthreads before stage 2 (t4s + w2s ready).

__global__ __launch_bounds__(512) void fused_shift_conv(
    const float* __restrict__ x,   // (512,14,14)
    const float* __restrict__ w1,  // (16,64,3)
    const float* __restrict__ w2,  // (32,8,3)
    float* __restrict__ out)       // (512,14,14)
{
    const int bx = blockIdx.x;     // 0..223
    const int m  = bx >> 4;        // 0..13
    const int o2 = bx & 15;        // 0..15  (== stage-1 output k)
    const int t  = threadIdx.x;    // 0..511

    __shared__ float w2s[32 * 8 * 3];  // full w2 (768 floats)
    __shared__ float t4s[112];         // t4[o2, j(=o), m, n]

    if (t < 224) {
        // ---- stage 1: 8*14 = 112 outputs as 56 float2, depth split 4-way ----
        const int quarter = t & 3;     // i in [16q, 16q+16)
        const int r  = t >> 2;         // 0..55
        const int o  = r / 7;          // 0..7  (group channel -> stage-2 'j')
        const int n0 = (r % 7) * 2;    // n pair base (0,2,..,12)
        const int ibase = quarter * 16;

        // w1 slice for this quarter: 48 contiguous floats, 16B-aligned.
        float4 w1v[12];
        {
            const float4* w1p = (const float4*)(w1 + (size_t)o2 * 192 + ibase * 3);
            #pragma unroll
            for (int q = 0; q < 12; ++q) w1v[q] = w1p[q];
        }

        // x slice: 48 float2 loads, all issued before any use (one latency round).
        float2 xv[3][16];
        #pragma unroll
        for (int j = 0; j < 3; ++j) {
            const int hp = m + j - 1;              // padded-H index (block-uniform)
            if (hp >= 0 && hp < 14) {
                const int row = (hp + 13) % 14;    // undo roll(+1)
                const float* xp = x + (size_t)(ibase * 8 + o) * 196 + row * 14 + n0;
                #pragma unroll
                for (int i = 0; i < 16; ++i)
                    xv[j][i] = *(const float2*)(xp + (size_t)i * 8 * 196);
            } else {
                #pragma unroll
                for (int i = 0; i < 16; ++i) xv[j][i] = make_float2(0.f, 0.f);
            }
        }

        float2 acc = make_float2(0.f, 0.f);
        const float* w1f = (const float*)w1v;      // static indices only (unrolled)
        #pragma unroll
        for (int j = 0; j < 3; ++j) {
            #pragma unroll
            for (int i = 0; i < 16; ++i) {
                const float w = w1f[i * 3 + j];
                acc.x += xv[j][i].x * w;
                acc.y += xv[j][i].y * w;
            }
        }

        // combine the 4 depth-partials within the quad (same wave, lanes 4r..4r+3)
        acc.x += __shfl_xor(acc.x, 1);
        acc.y += __shfl_xor(acc.y, 1);
        acc.x += __shfl_xor(acc.x, 2);
        acc.y += __shfl_xor(acc.y, 2);
        if (quarter == 0) *(float2*)(t4s + o * 14 + n0) = acc;  // 8B-aligned
    } else if (t >= 320) {
        // ---- waves 5-7 stage full w2 (192 float4), overlapped with stage 1 ----
        ((float4*)w2s)[t - 320] = ((const float4*)w2)[t - 320];
    }

    __syncthreads();   // the ONLY barrier: t4s + w2s ready

    // ---- stage 2: 32*14 = 448 outputs, one per thread ----
    if (t < 448) {
        const int n  = t % 14;
        const int i2 = t / 14;   // 0..31
        const float* wp = w2s + i2 * 24;
        float acc = 0.f;
        #pragma unroll
        for (int j = 0; j < 8; ++j) {
            const float* tp = t4s + j * 14;
            #pragma unroll
            for (int k = 0; k < 3; ++k) {
                const int nn = n + k - 1;
                if (nn >= 0 && nn < 14) acc += tp[nn] * wp[j * 3 + k];
            }
        }
        out[((size_t)(i2 * 16 + o2) * 14 + m) * 14 + n] = acc;
    }
}

extern "C" void kernel_launch(void* const* d_in, const int* in_sizes, int n_in,
                              void* d_out, int out_size, void* d_ws, size_t ws_size,
                              hipStream_t stream) {
    const float* x  = (const float*)d_in[0];
    const float* w1 = (const float*)d_in[1];
    const float* w2 = (const float*)d_in[2];
    float* out = (float*)d_out;
    fused_shift_conv<<<dim3(224), dim3(512), 0, stream>>>(x, w1, w2, out);
}

// Round 2
// 60.258 us; speedup vs baseline: 1.0540x; 1.0540x over previous
//
#include <hip/hip_runtime.h>

// Fused two-stage grouped conv, (1,512,14,14) fp32.
// Stage 1: t4[k,o,m,n] = sum_{i<64,j<3} x[(i*8+o), (m+j-2) mod 14, n] * w1[k,i,j]
//          (term valid only when 0 <= m+j-1 < 14; the mod-14 comes from roll(+1,H))
// Stage 2: out[i2*16+o2, m, n] = sum_{j<8,k<3} t4[o2,j,m,n+k-1] * w2[i2,j,k]  (zero-pad W)
//
// Latency-bound (14.5 MFLOP, ~0.8 MB real I/O; harness's 268 MB poison fill
// flushes L2+L3 every iteration -> all loads cold ~900cy).
// Design: ONE global-latency round, ONE barrier, max issuing width.
//  - 448 threads (7 waves), ALL issue loads at t=0: 48 scalar x loads
//    (round-0's proven coalesced mapping: adjacent lanes = adjacent n),
//    12x float4 w1 slice, 6x float4 w2 slice -> all registers, no weight LDS.
//  - Stage-1 partials stored as t4p[r][quarter] (contiguous float4);
//    stage-2 reads one ds_read_b128 per tap and folds the 4-way depth
//    reduction into its FMAs -> no combine step, no second/third barrier.

__global__ __launch_bounds__(448) void fused_shift_conv(
    const float* __restrict__ x,   // (512,14,14)
    const float* __restrict__ w1,  // (16,64,3)
    const float* __restrict__ w2,  // (32,8,3)
    float* __restrict__ out)       // (512,14,14)
{
    const int bx = blockIdx.x;     // 0..223
    const int m  = bx >> 4;        // 0..13
    const int o2 = bx & 15;        // 0..15  (== stage-1 output k)
    const int t  = threadIdx.x;    // 0..447

    __shared__ float t4p[112][4];  // [o*14+n][quarter] — 1.8 KB

    // ---- stage-1 identity (round-0 mapping: lanes contiguous in n) ----
    const int quarter = t / 112;   // i in [16q, 16q+16)
    const int r = t % 112;
    const int o = r / 14;          // 0..7  (group channel -> stage-2 'j')
    const int n = t % 14;          // == r % 14
    const int ibase = quarter * 16;
    // ---- stage-2 identity ----
    const int i2 = t / 14;         // 0..31

    // w2 slice -> registers (6 aligned float4; 96B per i2). Issued in the
    // same latency round as everything else; first used after the barrier.
    float4 w2v[6];
    {
        const float4* w2p = (const float4*)(w2 + (size_t)i2 * 24);
        #pragma unroll
        for (int q = 0; q < 6; ++q) w2v[q] = w2p[q];
    }

    // w1 slice for this quarter: 48 contiguous floats, 16B-aligned.
    float4 w1v[12];
    {
        const float4* w1p = (const float4*)(w1 + (size_t)o2 * 192 + ibase * 3);
        #pragma unroll
        for (int q = 0; q < 12; ++q) w1v[q] = w1p[q];
    }

    // x slice: 48 scalar loads, all independent, issued before any use.
    float xv[3][16];
    #pragma unroll
    for (int j = 0; j < 3; ++j) {
        const int hp = m + j - 1;              // padded-H index (block-uniform)
        if (hp >= 0 && hp < 14) {
            const int row = (hp + 13) % 14;    // undo roll(+1)
            const float* xp = x + (size_t)(ibase * 8 + o) * 196 + row * 14 + n;
            #pragma unroll
            for (int i = 0; i < 16; ++i)
                xv[j][i] = xp[(size_t)i * 8 * 196];
        } else {
            #pragma unroll
            for (int i = 0; i < 16; ++i) xv[j][i] = 0.f;
        }
    }

    // ---- stage-1 compute: 96 FMAs, depth-16 partial ----
    float acc1 = 0.f;
    const float* w1f = (const float*)w1v;      // static indices only (unrolled)
    #pragma unroll
    for (int j = 0; j < 3; ++j) {
        #pragma unroll
        for (int i = 0; i < 16; ++i) {
            acc1 += xv[j][i] * w1f[i * 3 + j];
        }
    }
    t4p[r][quarter] = acc1;

    __syncthreads();   // the ONLY barrier

    // ---- stage 2: 32*14 outputs, one per thread; 4-way depth fold fused ----
    const float* w2f = (const float*)w2v;
    float4 a4 = make_float4(0.f, 0.f, 0.f, 0.f);
    #pragma unroll
    for (int j = 0; j < 8; ++j) {
        #pragma unroll
        for (int k = 0; k < 3; ++k) {
            const int nn = n + k - 1;
            if (nn >= 0 && nn < 14) {
                const float4 p = *(const float4*)t4p[j * 14 + nn];  // b128, aligned
                const float w = w2f[j * 3 + k];
                a4.x += p.x * w; a4.y += p.y * w;
                a4.z += p.z * w; a4.w += p.w * w;
            }
        }
    }
    out[((size_t)(i2 * 16 + o2) * 14 + m) * 14 + n] = (a4.x + a4.y) + (a4.z + a4.w);
}

extern "C" void kernel_launch(void* const* d_in, const int* in_sizes, int n_in,
                              void* d_out, int out_size, void* d_ws, size_t ws_size,
                              hipStream_t stream) {
    const float* x  = (const float*)d_in[0];
    const float* w1 = (const float*)d_in[1];
    const float* w2 = (const float*)d_in[2];
    float* out = (float*)d_out;
    fused_shift_conv<<<dim3(224), dim3(448), 0, stream>>>(x, w1, w2, out);
}